// Round 2
// baseline (7906.671 us; speedup 1.0000x reference)
//
#include <hip/hip_runtime.h>
#include <hip/hip_bf16.h>
#include <stdint.h>

typedef unsigned short u16;
typedef __attribute__((ext_vector_type(8))) __bf16 bf16x8;
typedef __attribute__((ext_vector_type(4))) float  f32x4;

__device__ __forceinline__ float bf2f(u16 v) {
    union { unsigned int u; float f; } x; x.u = ((unsigned int)v) << 16; return x.f;
}
__device__ __forceinline__ u16 f2bf(float f) {
    union { float f; unsigned int u; } x; x.f = f;
    unsigned int u = x.u;
    unsigned int lsb = (u >> 16) & 1u;
    u += 0x7fffu + lsb;                      // round-to-nearest-even
    return (u16)(u >> 16);
}

#define GLDS16(gp, lp)                                                         \
    __builtin_amdgcn_global_load_lds(                                          \
        (const __attribute__((address_space(1))) void*)(gp),                   \
        (__attribute__((address_space(3))) void*)(lp), 16, 0, 0)

// ---------------------------------------------------------------------------
// fp32 -> bf16 conversion, 4 elements/thread
// ---------------------------------------------------------------------------
__global__ __launch_bounds__(256) void cvt_kernel(const float* __restrict__ src,
                                                  u16* __restrict__ dst, int n4)
{
    int gid = blockIdx.x * 256 + threadIdx.x;
    if (gid < n4) {
        float4 v = ((const float4*)src)[gid];
        ushort4 o;
        o.x = f2bf(v.x); o.y = f2bf(v.y); o.z = f2bf(v.z); o.w = f2bf(v.w);
        ((ushort4*)dst)[gid] = o;
    }
}

// ---------------------------------------------------------------------------
// Generic MFMA GEMM: C = act(scale * A @ B^T + bias) + residual
//   A: [M,K] bf16 row-major, row stride lda (elements)
//   B: [N,K] bf16 row-major (weight layout W[N][K]), row stride ldb
//   bias: fp32 (nullable). residual: fp32, row stride ldres (nullable)
//   C: [M,N], bf16 or fp32 (c_fp32), row stride ldc
//   batch: z -> z1 = z / zinner, z2 = z % zinner, offsets via strides
// Tile: 128x128, BK=32, 256 threads (4 waves, 2x2), 16x16x32 bf16 MFMA.
// M,N multiples of 128; K multiple of 32.
// ---------------------------------------------------------------------------
__global__ __launch_bounds__(256) void gemm_bt(
    const u16* __restrict__ A, const u16* __restrict__ B,
    const float* __restrict__ bias, const float* __restrict__ res,
    void* __restrict__ Cout, int c_fp32,
    int K, int lda, int ldb, int ldc, int ldres,
    long long sA1, long long sA2, long long sB1, long long sB2,
    long long sC1, long long sC2, int zinner, float scale, int act)
{
    __shared__ u16 As[128 * 32];
    __shared__ u16 Bs[128 * 32];

    int z  = blockIdx.z;
    int z1 = z / zinner;
    int z2 = z - z1 * zinner;
    A += z1 * sA1 + z2 * sA2;
    B += z1 * sB1 + z2 * sB2;
    long long coff = z1 * sC1 + z2 * sC2;

    int n0 = blockIdx.x << 7;
    int m0 = blockIdx.y << 7;

    int t = threadIdx.x;
    int w = t >> 6, l = t & 63;
    int wm = w >> 1, wn = w & 1;

    const u16* Ab = A + (long long)(m0 + w * 16 + (l >> 2)) * lda + ((l & 3) << 3);
    const u16* Bb = B + (long long)(n0 + w * 16 + (l >> 2)) * ldb + ((l & 3) << 3);
    long long a64 = (long long)64 * lda;
    long long b64 = (long long)64 * ldb;
    u16* AsW = &As[w << 9];
    u16* BsW = &Bs[w << 9];

    f32x4 acc[4][4];
#pragma unroll
    for (int i = 0; i < 4; i++)
#pragma unroll
        for (int j = 0; j < 4; j++)
            acc[i][j] = (f32x4){0.f, 0.f, 0.f, 0.f};

    int lk = (l >> 4) << 3;   // k offset 0/8/16/24
    int lr = l & 15;          // row (A) / col (B) within 16-tile

    for (int k0 = 0; k0 < K; k0 += 32) {
        GLDS16(Ab + k0,        AsW);
        GLDS16(Ab + k0 + a64,  AsW + 2048);
        GLDS16(Bb + k0,        BsW);
        GLDS16(Bb + k0 + b64,  BsW + 2048);
        __syncthreads();

        bf16x8 av[4], bv[4];
#pragma unroll
        for (int i = 0; i < 4; i++)
            av[i] = *(const bf16x8*)&As[((wm << 6) + (i << 4) + lr) * 32 + lk];
#pragma unroll
        for (int j = 0; j < 4; j++)
            bv[j] = *(const bf16x8*)&Bs[((wn << 6) + (j << 4) + lr) * 32 + lk];
#pragma unroll
        for (int i = 0; i < 4; i++)
#pragma unroll
            for (int j = 0; j < 4; j++)
                acc[i][j] = __builtin_amdgcn_mfma_f32_16x16x32_bf16(av[i], bv[j], acc[i][j], 0, 0, 0);
        __syncthreads();
    }

    // epilogue: C/D layout col = lane&15, row = (lane>>4)*4 + r
    int rq = (l >> 4) << 2;
#pragma unroll
    for (int j = 0; j < 4; j++) {
        int col = n0 + (wn << 6) + (j << 4) + lr;
        float bvv = bias ? bias[col] : 0.f;
#pragma unroll
        for (int i = 0; i < 4; i++) {
#pragma unroll
            for (int r = 0; r < 4; r++) {
                int row = m0 + (wm << 6) + (i << 4) + rq + r;
                float v = acc[i][j][r] * scale + bvv;
                if (act) v = 0.5f * v * (1.f + erff(v * 0.70710678118654752f));
                if (res) v += res[(long long)row * ldres + col];
                long long idx = coff + (long long)row * ldc + col;
                if (c_fp32) ((float*)Cout)[idx] = v;
                else        ((u16*)Cout)[idx]  = f2bf(v);
            }
        }
    }
}

// ---------------------------------------------------------------------------
// patch gather: x (8,1,512,512) fp32 -> patches [8192 tokens][256] bf16
// ---------------------------------------------------------------------------
__global__ __launch_bounds__(256) void patches_kernel(const float* __restrict__ x,
                                                      u16* __restrict__ p)
{
    int gid = blockIdx.x * 256 + threadIdx.x;      // 2,097,152 total
    int c = gid & 255, tk = gid >> 8;
    int b = tk >> 10, n = tk & 1023;
    int ph = n >> 5, pw = n & 31;
    int i = c >> 4, j = c & 15;
    p[gid] = f2bf(x[((long long)b << 18) + (long long)(ph * 16 + i) * 512 + pw * 16 + j]);
}

// ---------------------------------------------------------------------------
// positional encoding add (tok is fp32): pe[n][2j]=sin(ang), [2j+1]=cos(ang)
// ang = n / 10000^(j/256)
// ---------------------------------------------------------------------------
__global__ __launch_bounds__(256) void posenc_kernel(float* __restrict__ tok)
{
    int gid = blockIdx.x * 256 + threadIdx.x;      // 8,388,608 total
    int d = gid & 1023;
    int n = (gid >> 10) & 1023;
    int j = d >> 1;
    float ang = (float)n * exp2f(-13.287712379549449f * (float)j * (1.0f / 256.0f));
    float pe = (d & 1) ? cosf(ang) : sinf(ang);
    tok[gid] += pe;
}

// ---------------------------------------------------------------------------
// LayerNorm over last dim (1024): fp32 in, fp32 gamma/beta, bf16 out.
// ---------------------------------------------------------------------------
__global__ __launch_bounds__(256) void ln_kernel(const float* __restrict__ x,
                                                 const float* __restrict__ g,
                                                 const float* __restrict__ b,
                                                 u16* __restrict__ y)
{
    int row = blockIdx.x, t = threadIdx.x;
    const float* xr = x + (long long)row * 1024;
    float v[4]; float s = 0.f, ss = 0.f;
#pragma unroll
    for (int i = 0; i < 4; i++) { v[i] = xr[i * 256 + t]; s += v[i]; ss += v[i] * v[i]; }
    __shared__ float rs[256], rss[256];
    rs[t] = s; rss[t] = ss; __syncthreads();
    for (int o = 128; o > 0; o >>= 1) {
        if (t < o) { rs[t] += rs[t + o]; rss[t] += rss[t + o]; }
        __syncthreads();
    }
    float mean = rs[0] * (1.f / 1024.f);
    float var  = rss[0] * (1.f / 1024.f) - mean * mean;
    float rstd = rsqrtf(var + 1e-5f);
    u16* yr = y + (long long)row * 1024;
#pragma unroll
    for (int i = 0; i < 4; i++) {
        int d = i * 256 + t;
        yr[d] = f2bf((v[i] - mean) * rstd * g[d] + b[d]);
    }
}

// ---------------------------------------------------------------------------
// softmax in-place over rows of 1024 (bf16), one block per row
// ---------------------------------------------------------------------------
__global__ __launch_bounds__(256) void softmax_kernel(u16* __restrict__ sc)
{
    int row = blockIdx.x, t = threadIdx.x;
    u16* p = sc + (long long)row * 1024;
    float v[4]; float mx = -1e30f;
#pragma unroll
    for (int i = 0; i < 4; i++) { v[i] = bf2f(p[i * 256 + t]); mx = fmaxf(mx, v[i]); }
    __shared__ float red[256];
    red[t] = mx; __syncthreads();
    for (int o = 128; o > 0; o >>= 1) {
        if (t < o) red[t] = fmaxf(red[t], red[t + o]);
        __syncthreads();
    }
    mx = red[0]; __syncthreads();
    float sum = 0.f;
#pragma unroll
    for (int i = 0; i < 4; i++) { v[i] = expf(v[i] - mx); sum += v[i]; }
    red[t] = sum; __syncthreads();
    for (int o = 128; o > 0; o >>= 1) {
        if (t < o) red[t] += red[t + o];
        __syncthreads();
    }
    float inv = 1.f / red[0];
#pragma unroll
    for (int i = 0; i < 4; i++) p[i * 256 + t] = f2bf(v[i] * inv);
}

// ---------------------------------------------------------------------------
// V transpose: qkv[token][2048 + head*128 + d] -> vt[bh][d][n]  (bh = b*8+head)
// ---------------------------------------------------------------------------
__global__ __launch_bounds__(256) void vt_kernel(const u16* __restrict__ qkv,
                                                 u16* __restrict__ vt)
{
    int bh   = blockIdx.x >> 4;
    int tile = blockIdx.x & 15;
    int b = bh >> 3, hd = bh & 7;
    int t = threadIdx.x;
    __shared__ u16 tl[64][130];
    int nk0 = tile * 64;
    int dcol = t & 127, r0 = t >> 7;     // r0 in {0,1}
    const u16* src = qkv + ((long long)(b * 1024 + nk0)) * 3072 + 2048 + hd * 128 + dcol;
#pragma unroll
    for (int r = 0; r < 32; r++) {
        int nk = r0 + r * 2;
        tl[nk][dcol] = src[(long long)nk * 3072];
    }
    __syncthreads();
    u16* dst = vt + ((long long)bh * 128) * 1024 + nk0;
#pragma unroll
    for (int r = 0; r < 32; r++) {
        int flat = r * 256 + t;          // 0..8191
        int d = flat >> 6, nk = flat & 63;
        dst[(long long)d * 1024 + nk] = tl[nk][d];
    }
}

// ---------------------------------------------------------------------------
// reconstruction: tok fp32 [8192][1024] -> out fp32 (8,1,1024,1024)
// ---------------------------------------------------------------------------
__global__ __launch_bounds__(256) void recon_kernel(const float* __restrict__ tok,
                                                    float* __restrict__ out)
{
    int gid = blockIdx.x * 256 + threadIdx.x;      // 8,388,608
    int b  = gid >> 20;
    int y  = (gid >> 10) & 1023;
    int xx = gid & 1023;
    int p1 = y & 1,  hh = y >> 1,  a  = hh >> 4, i = hh & 15;
    int p2 = xx & 1, wv = xx >> 1, bb = wv >> 4, j = wv & 15;
    int n = a * 32 + bb;
    int d = ((i * 16 + j) << 2) + (p1 << 1) + p2;
    out[gid] = tok[((long long)(b * 1024 + n) << 10) + d];
}

// ---------------------------------------------------------------------------
extern "C" void kernel_launch(void* const* d_in, const int* in_sizes, int n_in,
                              void* d_out, int out_size, void* d_ws, size_t ws_size,
                              hipStream_t stream)
{
    (void)in_sizes; (void)n_in; (void)out_size; (void)ws_size;
    const float* x      = (const float*)d_in[0];
    const float* conv_w = (const float*)d_in[1];
    const float* conv_b = (const float*)d_in[2];
    const float* ln1_g  = (const float*)d_in[3];
    const float* ln1_b  = (const float*)d_in[4];
    const float* qkv_w  = (const float*)d_in[5];
    const float* qkv_b  = (const float*)d_in[6];
    const float* proj_w = (const float*)d_in[7];
    const float* proj_b = (const float*)d_in[8];
    const float* ln2_g  = (const float*)d_in[9];
    const float* ln2_b  = (const float*)d_in[10];
    const float* qkv_wf = qkv_w;
    const float* fc1_w  = (const float*)d_in[11];
    const float* fc1_b  = (const float*)d_in[12];
    const float* fc2_w  = (const float*)d_in[13];
    const float* fc2_b  = (const float*)d_in[14];
    (void)qkv_wf;

    char* ws = (char*)d_ws;
    float* tokf  = (float*)ws;                         // 33,554,432 B
    u16* h       = (u16*)(ws + 33554432);              // 16,777,216
    u16* qkvb    = (u16*)(ws + 50331648);              // 50,331,648
    u16* vt      = (u16*)(ws + 100663296);             // 16,777,216
    u16* attnout = (u16*)(ws + 117440512);             // 16,777,216
    u16* mid     = (u16*)(ws + 134217728);             // 33,554,432 (aliased with scores)
    u16* scores  = (u16*)(ws + 134217728);             // alias: disjoint lifetime vs mid
    u16* patches = (u16*)(ws + 167772160);             //  4,194,304
    u16* convw   = (u16*)(ws + 171966464);             //    524,288
    u16* wqkv    = (u16*)(ws + 172490752);             //  6,291,456
    u16* wproj   = (u16*)(ws + 178782208);             //  2,097,152
    u16* wfc1    = (u16*)(ws + 180879360);             //  4,194,304
    u16* wfc2    = (u16*)(ws + 185073664);             //  4,194,304  (end 189,267,968)

    dim3 blk(256);
    const float attn_scale = 0.08838834764831845f;   // 128^-0.5

    // ---- patch embed ----
    patches_kernel<<<dim3(8192), blk, 0, stream>>>(x, patches);
    cvt_kernel<<<dim3(256), blk, 0, stream>>>(conv_w, convw, 65536);
    gemm_bt<<<dim3(8, 64, 1), blk, 0, stream>>>(
        patches, convw, conv_b, (const float*)nullptr, (void*)tokf, 1,
        256, 256, 256, 1024, 0, 0LL, 0LL, 0LL, 0LL, 0LL, 0LL, 1, 1.0f, 0);
    posenc_kernel<<<dim3(32768), blk, 0, stream>>>(tokf);

    // ---- transformer layers ----
    for (int L = 0; L < 12; L++) {
        cvt_kernel<<<dim3(3072), blk, 0, stream>>>(qkv_w + (long long)L * 3145728, wqkv, 786432);
        cvt_kernel<<<dim3(1024), blk, 0, stream>>>(proj_w + (long long)L * 1048576, wproj, 262144);
        cvt_kernel<<<dim3(2048), blk, 0, stream>>>(fc1_w + (long long)L * 2097152, wfc1, 524288);
        cvt_kernel<<<dim3(2048), blk, 0, stream>>>(fc2_w + (long long)L * 2097152, wfc2, 524288);

        ln_kernel<<<dim3(8192), blk, 0, stream>>>(
            tokf, ln1_g + L * 1024, ln1_b + L * 1024, h);

        gemm_bt<<<dim3(24, 64, 1), blk, 0, stream>>>(
            h, wqkv, qkv_b + L * 3072,
            (const float*)nullptr, (void*)qkvb, 0,
            1024, 1024, 1024, 3072, 0, 0LL, 0LL, 0LL, 0LL, 0LL, 0LL, 1, 1.0f, 0);

        vt_kernel<<<dim3(1024), blk, 0, stream>>>(qkvb, vt);

        for (int c = 0; c < 4; c++) {   // 16 (b,head) pairs per chunk = 2 batches
            const u16* qbase = qkvb + (long long)(2 * c) * 1024 * 3072;
            // scores = scale * Q @ K^T   [16 x 1024 x 1024]
            gemm_bt<<<dim3(8, 8, 16), blk, 0, stream>>>(
                qbase, qbase + 1024, (const float*)nullptr, (const float*)nullptr,
                (void*)scores, 0,
                128, 3072, 3072, 1024, 0,
                3145728LL, 128LL, 3145728LL, 128LL, 8388608LL, 1048576LL,
                8, attn_scale, 0);
            softmax_kernel<<<dim3(16384), blk, 0, stream>>>(scores);
            // O = P @ V  (vt rows are d, cols are keys)
            gemm_bt<<<dim3(1, 8, 16), blk, 0, stream>>>(
                scores, vt + (long long)c * 2097152, (const float*)nullptr,
                (const float*)nullptr,
                (void*)(attnout + (long long)(2 * c) * 1048576), 0,
                1024, 1024, 1024, 1024, 0,
                8388608LL, 1048576LL, 1048576LL, 131072LL, 1048576LL, 128LL,
                8, 1.0f, 0);
        }

        // tok += attnout @ proj_w^T + proj_b   (fp32 residual/out)
        gemm_bt<<<dim3(8, 64, 1), blk, 0, stream>>>(
            attnout, wproj, proj_b + L * 1024,
            tokf, (void*)tokf, 1,
            1024, 1024, 1024, 1024, 1024, 0LL, 0LL, 0LL, 0LL, 0LL, 0LL, 1, 1.0f, 0);

        ln_kernel<<<dim3(8192), blk, 0, stream>>>(
            tokf, ln2_g + L * 1024, ln2_b + L * 1024, h);

        // mid = gelu(h @ fc1^T + b1)
        gemm_bt<<<dim3(16, 64, 1), blk, 0, stream>>>(
            h, wfc1, fc1_b + L * 2048,
            (const float*)nullptr, (void*)mid, 0,
            1024, 1024, 1024, 2048, 0, 0LL, 0LL, 0LL, 0LL, 0LL, 0LL, 1, 1.0f, 1);

        // tok += mid @ fc2^T + b2
        gemm_bt<<<dim3(8, 64, 1), blk, 0, stream>>>(
            mid, wfc2, fc2_b + L * 1024,
            tokf, (void*)tokf, 1,
            2048, 2048, 2048, 1024, 1024, 0LL, 0LL, 0LL, 0LL, 0LL, 0LL, 1, 1.0f, 0);
    }

    // ---- reconstruction ----
    recon_kernel<<<dim3(32768), blk, 0, stream>>>(tokf, (float*)d_out);
}